// Round 21
// baseline (168.581 us; speedup 1.0000x reference)
//
#include <hip/hip_runtime.h>
#include <hip/hip_bf16.h>

#define SVOL 110592   // 48*48*48 voxels
#define HD   2304     // 48*48
#define NDIM 48

typedef __attribute__((ext_vector_type(4))) float f32x4;
typedef __attribute__((ext_vector_type(8))) short bf16x8;
typedef __attribute__((ext_vector_type(2))) unsigned int u32x2;
typedef unsigned short ushort_t;
typedef unsigned int uint_t;

__device__ __forceinline__ ushort_t f2b(float f) {
    __hip_bfloat16 h = __float2bfloat16(f);
    return *(ushort_t*)&h;
}
__device__ __forceinline__ float b2f(uint_t u) {   // u = bf16 bits in low 16
    union { float f; uint_t i; } v; v.i = u << 16; return v.f;
}

// ---------------- Kernel 0: W fp32 -> bf16 ----------------
__global__ __launch_bounds__(256) void wconv_kernel(const float* __restrict__ W,
                                                    ushort_t* __restrict__ Wb) {
    int i = blockIdx.x * 256 + threadIdx.x;   // 128*256 = 32768 exactly
    Wb[i] = f2b(W[i]);
}

// ---------------- Kernel 1: parity-min tables (bf16 out) ----------------
// tabDp[part][bc][p][h*48+w] (partial), tabH[bc][p][d*48+w], tabW[bc][p][d*48+h]
__global__ __launch_bounds__(256) void tables_kernel(const float* __restrict__ x,
                                                     ushort_t* __restrict__ tabDp,
                                                     ushort_t* __restrict__ tabH,
                                                     ushort_t* __restrict__ tabW) {
    __shared__ __align__(16) float sl[4 * HD];   // 36 KB: 4 planes, linear
    const int bc   = blockIdx.x;
    const int part = blockIdx.y;     // 0..2
    const float* __restrict__ xp = x + (size_t)bc * SVOL + (size_t)part * 16 * HD;
    const int t    = threadIdx.x;
    const int w4   = t >> 6;         // wave 0..3
    const int lane = t & 63;
    const int dlh  = t / NDIM;       // H/W task split (t < 192): plane-local d
    const int wh   = t - dlh * NDIM; // 0..47

    f32x4 accD[3][2];
    #pragma unroll
    for (int s = 0; s < 3; ++s)
        #pragma unroll
        for (int p = 0; p < 2; ++p)
            #pragma unroll
            for (int e = 0; e < 4; ++e) accD[s][p][e] = 3e38f;

    for (int q = 0; q < 4; ++q) {
        const float* __restrict__ qp = xp + (size_t)q * 4 * HD;
        #pragma unroll
        for (int k = 0; k < 9; ++k) {
            const int i16 = (k * 4 + w4) * 64 + lane;
            __builtin_amdgcn_global_load_lds(
                (const __attribute__((address_space(1))) void*)(qp + (size_t)i16 * 4),
                (__attribute__((address_space(3))) void*)&sl[(k * 4 + w4) * 256],
                16, 0, 0);
        }
        __syncthreads();

        #pragma unroll
        for (int s = 0; s < 3; ++s) {
            const int j = t + s * 256;
            if (j < 576) {
                #pragma unroll
                for (int dl = 0; dl < 4; ++dl) {
                    f32x4 v = ((const f32x4*)sl)[dl * 576 + j];
                    #pragma unroll
                    for (int e = 0; e < 4; ++e)
                        accD[s][dl & 1][e] = fminf(accD[s][dl & 1][e], v[e]);
                }
            }
        }
        if (t < 192) {
            const int d = part * 16 + q * 4 + dlh;
            {   // H: min over h at fixed (dlh, w=wh)
                const float* pb = sl + dlh * HD + wh;
                float m0 = 3e38f, m1 = 3e38f;
                #pragma unroll
                for (int h = 0; h < NDIM; h += 2) {
                    m0 = fminf(m0, pb[h * NDIM]);
                    m1 = fminf(m1, pb[(h + 1) * NDIM]);
                }
                tabH[(size_t)bc * 2 * HD + d * NDIM + wh]      = f2b(m0);
                tabH[(size_t)bc * 2 * HD + HD + d * NDIM + wh] = f2b(m1);
            }
            {   // W: min over w at fixed (dlh, h=wh)
                const f32x4* pr = (const f32x4*)(sl + dlh * HD + wh * NDIM);
                const int rot = wh % 12;
                float m0 = 3e38f, m1 = 3e38f;
                #pragma unroll
                for (int j = 0; j < 12; ++j) {
                    int jj = j + rot; if (jj >= 12) jj -= 12;
                    f32x4 v = pr[jj];
                    m0 = fminf(m0, fminf(v[0], v[2]));
                    m1 = fminf(m1, fminf(v[1], v[3]));
                }
                tabW[(size_t)bc * 2 * HD + d * NDIM + wh]      = f2b(m0);
                tabW[(size_t)bc * 2 * HD + HD + d * NDIM + wh] = f2b(m1);
            }
        }
        __syncthreads();
    }

    ushort_t* tDo = tabDp + ((size_t)part * 256 + bc) * 2 * HD;
    #pragma unroll
    for (int s = 0; s < 3; ++s) {
        const int j = t + s * 256;
        if (j < 576) {
            union { ushort_t s4[4]; uint2 u; } p0, p1;
            #pragma unroll
            for (int e = 0; e < 4; ++e) { p0.s4[e] = f2b(accD[s][0][e]); p1.s4[e] = f2b(accD[s][1][e]); }
            *(uint2*)(tDo + j * 4)      = p0.u;
            *(uint2*)(tDo + HD + j * 4) = p1.u;
        }
    }
}

// ---------------- Kernel 2: merge 3 bf16 tabD partials -> tabD ----------------
__global__ __launch_bounds__(256) void merge_kernel(const ushort_t* __restrict__ tabDp,
                                                    ushort_t* __restrict__ tabD) {
    const int i = blockIdx.x * 256 + threadIdx.x;    // uint2 id, 294912 total
    const size_t off = (size_t)256 * 2 * HD / 4;     // partial stride in uint2
    union U { uint2 u; ushort_t s4[4]; } a, b1, c, o;
    a.u  = ((const uint2*)tabDp)[i];
    b1.u = ((const uint2*)tabDp)[i + off];
    c.u  = ((const uint2*)tabDp)[i + 2 * off];
    #pragma unroll
    for (int j = 0; j < 4; ++j)
        o.s4[j] = f2b(fminf(b2f(a.s4[j]), fminf(b2f(b1.s4[j]), b2f(c.s4[j]))));
    ((uint2*)tabD)[i] = o.u;
}

// ---------------- Kernel 3: fused xj + GEMM, BARRIER-FREE wave-private tiles ----------------
// Each wave owns a 128o x 16s tile and a private 8 KB LDS quadrant:
// stage own 16s -> ds_write own quadrant -> lgkmcnt(0) (same-wave write->read
// needs NO barrier) -> 16 tr_reads -> 64 MFMA -> store. Zero __syncthreads.
// Quadrant layout: [cq 0..63][row=c&3][col=s&15] ushort, cq stride 128 B
// (x -> cq 0..31, xj -> cq 32..63). tr_read for (kk,l4): byte =
// qbase + kk*1024 + l4*256 + l15*8, pair offset:0/128 -> lane gets channels
// kk*32 + l4*8 + 0..7 at s-col l15 (same verified frag layout as R20).
__global__ __launch_bounds__(256) void gemm_kernel(const float* __restrict__ x,
                                                   const ushort_t* __restrict__ tabD,
                                                   const ushort_t* __restrict__ tabH,
                                                   const ushort_t* __restrict__ tabW,
                                                   const ushort_t* __restrict__ Wb,
                                                   const float* __restrict__ bias,
                                                   float* __restrict__ out) {
    __shared__ __align__(1024) ushort_t ytile[4 * 4096];   // 4 waves x 8 KB
    const int bx  = blockIdx.x;                   // 0..1727
    const int b   = blockIdx.y;
    const int swz = (bx & 7) * 216 + (bx >> 3);   // bijective: 1728 = 8*216
    const int t   = threadIdx.x;
    const int wid = t >> 6, lane = t & 63;
    const int s4   = lane & 3;            // s-quad within the 16-s tile
    const int cgrp = lane >> 2;           // 0..15
    const int l15 = lane & 15, l4 = lane >> 4;

    // geometry: block = 64 s (4 waves x 16); 64 | 2304 -> single d-plane
    const int d  = (swz * 64) / HD;
    const int rb = swz * 64 - d * HD;
    const int pd = d & 1;
    const int r_t = rb + wid * 16 + s4 * 4;   // this thread's r quad (mult of 4)
    const int h   = r_t / NDIM;
    const int w0  = r_t - h * NDIM;
    const int ph  = h & 1;
    const int sg  = d * HD + r_t;             // global s of quad start

    const float* __restrict__ xb = x + (size_t)b * 128 * SVOL;
    const size_t tbb = (size_t)b * 128 * 2 * HD;

    // ---- stage own 16 s, write own quadrant (no barrier ever) ----
    ushort_t* q = &ytile[wid * 4096];
    #pragma unroll
    for (int it = 0; it < 8; ++it) {
        const int c = it * 16 + cgrp;
        const size_t tb = tbb + (size_t)c * 2 * HD;
        f32x4 xv  = *(const f32x4*)(xb + (size_t)c * SVOL + sg);
        uint2 md2 = *(const uint2*)(tabD + tb + (size_t)pd * HD + r_t);
        uint2 mh2 = *(const uint2*)(tabH + tb + (size_t)ph * HD + d * NDIM + w0);
        const float mW0 = b2f(tabW[tb + d * NDIM + h]);
        const float mW1 = b2f(tabW[tb + HD + d * NDIM + h]);
        float mD[4] = { b2f(md2.x & 0xffffu), b2f(md2.x >> 16),
                        b2f(md2.y & 0xffffu), b2f(md2.y >> 16) };
        float mH[4] = { b2f(mh2.x & 0xffffu), b2f(mh2.x >> 16),
                        b2f(mh2.y & 0xffffu), b2f(mh2.y >> 16) };
        union { __hip_bfloat16 h4[4]; uint2 u; } ox, oj;
        #pragma unroll
        for (int j = 0; j < 4; ++j) {
            const float mm = fminf(mD[j], fminf(mH[j], (j & 1) ? mW1 : mW0));
            ox.h4[j] = __float2bfloat16(xv[j]);
            oj.h4[j] = __float2bfloat16(fmaxf(0.0f, xv[j] - mm));
        }
        const int aoff = (c >> 2) * 64 + (c & 3) * 16 + s4 * 4;   // ushort units
        *(uint2*)&q[aoff]        = ox.u;    // x:  cq 0..31
        *(uint2*)&q[aoff + 2048] = oj.u;    // xj: cq 32..63 (+4 KB)
    }
    asm volatile("s_waitcnt lgkmcnt(0)" ::: "memory");   // own writes landed
    __builtin_amdgcn_sched_barrier(0);

    // ---- tr_read all 8 kk B-fragments (16 reads) ----
    const uint_t qbyte = (uint_t)(uintptr_t)(__attribute__((address_space(3))) ushort_t*)&ytile[0]
                       + (uint_t)(wid * 8192 + l4 * 256 + l15 * 8);
    u32x2 lo[8], hi[8];
    #pragma unroll
    for (int kk = 0; kk < 8; ++kk) {
        const uint_t ad = qbyte + (uint_t)(kk * 1024);
        asm volatile("ds_read_b64_tr_b16 %0, %2 offset:0\n\t"
                     "ds_read_b64_tr_b16 %1, %2 offset:128"
                     : "=&v"(lo[kk]), "=&v"(hi[kk]) : "v"(ad) : "memory");
    }
    asm volatile("s_waitcnt lgkmcnt(0)" ::: "memory");
    __builtin_amdgcn_sched_barrier(0);

    // ---- 64 MFMA: 8 kk x 8 o-frags (W streams from L1/L2) ----
    const ushort_t* __restrict__ wp = Wb + (size_t)l15 * 256 + l4 * 8;
    f32x4 acc[8] = {};
    #pragma unroll
    for (int kk = 0; kk < 8; ++kk) {
        union { u32x2 u2[2]; bf16x8 v; } cvt;
        cvt.u2[0] = lo[kk]; cvt.u2[1] = hi[kk];
        #pragma unroll
        for (int m = 0; m < 8; ++m) {
            bf16x8 aw = *(const bf16x8*)(wp + ((size_t)m * 16 * 256 + kk * 32));
            acc[m] = __builtin_amdgcn_mfma_f32_16x16x32_bf16(cvt.v, aw, acc[m], 0, 0, 0);
        }
    }

    // ---- epilogue: D rows = s (l4*4+j), cols = o (l15) ----
    float* ob = out + (size_t)b * 128 * SVOL;
    const int s_st = d * HD + rb + wid * 16 + l4 * 4;
    #pragma unroll
    for (int m = 0; m < 8; ++m) {
        const int o = m * 16 + l15;
        const float bv = bias[o];
        f32x4 r;
        #pragma unroll
        for (int j = 0; j < 4; ++j) r[j] = fmaxf(acc[m][j] + bv, 0.0f);
        *(f32x4*)(ob + (size_t)o * SVOL + s_st) = r;
    }
}

extern "C" void kernel_launch(void* const* d_in, const int* in_sizes, int n_in,
                              void* d_out, int out_size, void* d_ws, size_t ws_size,
                              hipStream_t stream) {
    const float* x    = (const float*)d_in[0];
    const float* W    = (const float*)d_in[1];
    const float* bias = (const float*)d_in[2];
    float* out = (float*)d_out;

    // d_ws (all bf16): Wb 64 KB | tabDp 6.75 MB | tabH 2.25 | tabW 2.25 | tabD 2.25
    ushort_t* Wb    = (ushort_t*)d_ws;
    ushort_t* tabDp = (ushort_t*)((char*)d_ws + 65536);
    ushort_t* tabH  = tabDp + (size_t)3 * 256 * 2 * HD;
    ushort_t* tabW  = tabH  + (size_t)256 * 2 * HD;
    ushort_t* tabD  = tabW  + (size_t)256 * 2 * HD;

    wconv_kernel<<<128, 256, 0, stream>>>(W, Wb);
    tables_kernel<<<dim3(256, 3), 256, 0, stream>>>(x, tabDp, tabH, tabW);
    merge_kernel<<<1152, 256, 0, stream>>>(tabDp, tabD);
    gemm_kernel<<<dim3(1728, 2), 256, 0, stream>>>(x, tabD, tabH, tabW, Wb, bias, out);
}

// Round 22
// 112.606 us; speedup vs baseline: 1.4971x; 1.4971x over previous
//
#include <hip/hip_runtime.h>
#include <hip/hip_bf16.h>

#define SVOL 110592   // 48*48*48 voxels
#define HD   2304     // 48*48
#define NDIM 48

typedef __attribute__((ext_vector_type(4))) float f32x4;
typedef __attribute__((ext_vector_type(8))) short bf16x8;
typedef __attribute__((ext_vector_type(2))) unsigned int u32x2;
typedef unsigned short ushort_t;
typedef unsigned int uint_t;

__device__ __forceinline__ ushort_t f2b(float f) {
    __hip_bfloat16 h = __float2bfloat16(f);
    return *(ushort_t*)&h;
}
__device__ __forceinline__ float b2f(uint_t u) {   // u = bf16 bits in low 16
    union { float f; uint_t i; } v; v.i = u << 16; return v.f;
}

// ---------------- Kernel 0: W fp32 -> bf16 ----------------
__global__ __launch_bounds__(256) void wconv_kernel(const float* __restrict__ W,
                                                    ushort_t* __restrict__ Wb) {
    int i = blockIdx.x * 256 + threadIdx.x;   // 128*256 = 32768 exactly
    Wb[i] = f2b(W[i]);
}

// ---------------- Kernel 1: parity-min tables (bf16 out) ----------------
// tabDp[part][bc][p][h*48+w] (partial), tabH[bc][p][d*48+w], tabW[bc][p][d*48+h]
__global__ __launch_bounds__(256) void tables_kernel(const float* __restrict__ x,
                                                     ushort_t* __restrict__ tabDp,
                                                     ushort_t* __restrict__ tabH,
                                                     ushort_t* __restrict__ tabW) {
    __shared__ __align__(16) float sl[4 * HD];   // 36 KB: 4 planes, linear
    const int bc   = blockIdx.x;
    const int part = blockIdx.y;     // 0..2
    const float* __restrict__ xp = x + (size_t)bc * SVOL + (size_t)part * 16 * HD;
    const int t    = threadIdx.x;
    const int w4   = t >> 6;         // wave 0..3
    const int lane = t & 63;
    const int dlh  = t / NDIM;       // H/W task split (t < 192): plane-local d
    const int wh   = t - dlh * NDIM; // 0..47

    f32x4 accD[3][2];
    #pragma unroll
    for (int s = 0; s < 3; ++s)
        #pragma unroll
        for (int p = 0; p < 2; ++p)
            #pragma unroll
            for (int e = 0; e < 4; ++e) accD[s][p][e] = 3e38f;

    for (int q = 0; q < 4; ++q) {
        const float* __restrict__ qp = xp + (size_t)q * 4 * HD;
        #pragma unroll
        for (int k = 0; k < 9; ++k) {
            const int i16 = (k * 4 + w4) * 64 + lane;
            __builtin_amdgcn_global_load_lds(
                (const __attribute__((address_space(1))) void*)(qp + (size_t)i16 * 4),
                (__attribute__((address_space(3))) void*)&sl[(k * 4 + w4) * 256],
                16, 0, 0);
        }
        __syncthreads();

        #pragma unroll
        for (int s = 0; s < 3; ++s) {
            const int j = t + s * 256;
            if (j < 576) {
                #pragma unroll
                for (int dl = 0; dl < 4; ++dl) {
                    f32x4 v = ((const f32x4*)sl)[dl * 576 + j];
                    #pragma unroll
                    for (int e = 0; e < 4; ++e)
                        accD[s][dl & 1][e] = fminf(accD[s][dl & 1][e], v[e]);
                }
            }
        }
        if (t < 192) {
            const int d = part * 16 + q * 4 + dlh;
            {   // H: min over h at fixed (dlh, w=wh)
                const float* pb = sl + dlh * HD + wh;
                float m0 = 3e38f, m1 = 3e38f;
                #pragma unroll
                for (int h = 0; h < NDIM; h += 2) {
                    m0 = fminf(m0, pb[h * NDIM]);
                    m1 = fminf(m1, pb[(h + 1) * NDIM]);
                }
                tabH[(size_t)bc * 2 * HD + d * NDIM + wh]      = f2b(m0);
                tabH[(size_t)bc * 2 * HD + HD + d * NDIM + wh] = f2b(m1);
            }
            {   // W: min over w at fixed (dlh, h=wh)
                const f32x4* pr = (const f32x4*)(sl + dlh * HD + wh * NDIM);
                const int rot = wh % 12;
                float m0 = 3e38f, m1 = 3e38f;
                #pragma unroll
                for (int j = 0; j < 12; ++j) {
                    int jj = j + rot; if (jj >= 12) jj -= 12;
                    f32x4 v = pr[jj];
                    m0 = fminf(m0, fminf(v[0], v[2]));
                    m1 = fminf(m1, fminf(v[1], v[3]));
                }
                tabW[(size_t)bc * 2 * HD + d * NDIM + wh]      = f2b(m0);
                tabW[(size_t)bc * 2 * HD + HD + d * NDIM + wh] = f2b(m1);
            }
        }
        __syncthreads();
    }

    ushort_t* tDo = tabDp + ((size_t)part * 256 + bc) * 2 * HD;
    #pragma unroll
    for (int s = 0; s < 3; ++s) {
        const int j = t + s * 256;
        if (j < 576) {
            union { ushort_t s4[4]; uint2 u; } p0, p1;
            #pragma unroll
            for (int e = 0; e < 4; ++e) { p0.s4[e] = f2b(accD[s][0][e]); p1.s4[e] = f2b(accD[s][1][e]); }
            *(uint2*)(tDo + j * 4)      = p0.u;
            *(uint2*)(tDo + HD + j * 4) = p1.u;
        }
    }
}

// ---------------- Kernel 2: merge 3 bf16 tabD partials -> tabD ----------------
__global__ __launch_bounds__(256) void merge_kernel(const ushort_t* __restrict__ tabDp,
                                                    ushort_t* __restrict__ tabD) {
    const int i = blockIdx.x * 256 + threadIdx.x;    // uint2 id, 294912 total
    const size_t off = (size_t)256 * 2 * HD / 4;     // partial stride in uint2
    union U { uint2 u; ushort_t s4[4]; } a, b1, c, o;
    a.u  = ((const uint2*)tabDp)[i];
    b1.u = ((const uint2*)tabDp)[i + off];
    c.u  = ((const uint2*)tabDp)[i + 2 * off];
    #pragma unroll
    for (int j = 0; j < 4; ++j)
        o.s4[j] = f2b(fminf(b2f(a.s4[j]), fminf(b2f(b1.s4[j]), b2f(c.s4[j]))));
    ((uint2*)tabD)[i] = o.u;
}

// ---------------- Kernel 3: fused xj + GEMM (R20 body, TPB=1) ----------------
// Tile 128o x 64s; LDS 32 KB single buffer; ONE tile per block so the grid is
// 3456 fully independent blocks (13.5/CU) -- the only lever that has ever
// moved this kernel (R17: TPB 4->2 = +16%) taken to its limit. Per-block
// chain: stage -> ds_write -> barrier -> 4x(tr+MFMA) -> store. 64 | 2304 so
// each block stays in one d-plane.
__global__ __launch_bounds__(256) void gemm_kernel(const float* __restrict__ x,
                                                   const ushort_t* __restrict__ tabD,
                                                   const ushort_t* __restrict__ tabH,
                                                   const ushort_t* __restrict__ tabW,
                                                   const ushort_t* __restrict__ Wb,
                                                   const float* __restrict__ bias,
                                                   float* __restrict__ out) {
    __shared__ __align__(1024) ushort_t ytile[16384];   // 32 KB
    const int bx  = blockIdx.x;                   // 0..1727
    const int b   = blockIdx.y;
    const int tile0 = (bx & 7) * 216 + (bx >> 3); // bijective: 1728 = 8*216
    const int t  = threadIdx.x;
    const int wid = t >> 6, lane = t & 63;   // 4 waves
    const int row  = lane & 3;               // c & 3
    const int colq = (lane >> 2) & 3;        // col quad
    const int sqq  = (lane >> 4) & 3;        // sq
    const int sloc = (sqq * 4 + colq) * 4;   // s within tile, mult of 4
    const int l15 = lane & 15, l4 = lane >> 4;

    const float* __restrict__ xb = x + (size_t)b * 128 * SVOL;
    const size_t tbb = (size_t)b * 128 * 2 * HD;   // table base (ushort units)

    const ushort_t* wp = Wb + (size_t)(wid * 32 + l15) * 256 + l4 * 8;
    float bv[2];
    #pragma unroll
    for (int m = 0; m < 2; ++m) bv[m] = bias[wid * 32 + m * 16 + l15];

    // plane geometry (64 | 2304 -> single d-plane per block)
    const int d  = (tile0 * 64) / HD;
    const int rb = tile0 * 64 - d * HD;      // r of this tile's first voxel
    const int pd = d & 1;

    // ---- stage this block's 64 s ----
    uint2 pk[8][2];
    {
        const int r  = rb + sloc;
        const int h  = r / NDIM;
        const int w0 = r - h * NDIM;
        const int ph = h & 1;
        const int s  = d * HD + r;
        #pragma unroll
        for (int it = 0; it < 8; ++it) {
            const int c = (it * 4 + wid) * 4 + row;
            const size_t tb = tbb + (size_t)c * 2 * HD;
            f32x4 xv = *(const f32x4*)(xb + (size_t)c * SVOL + s);
            uint2 md2 = *(const uint2*)(tabD + tb + pd * HD + r);
            uint2 mh2 = *(const uint2*)(tabH + tb + ph * HD + d * NDIM + w0);
            const float mW0 = b2f(tabW[tb + d * NDIM + h]);
            const float mW1 = b2f(tabW[tb + HD + d * NDIM + h]);
            float mD[4] = { b2f(md2.x & 0xffffu), b2f(md2.x >> 16),
                            b2f(md2.y & 0xffffu), b2f(md2.y >> 16) };
            float mH[4] = { b2f(mh2.x & 0xffffu), b2f(mh2.x >> 16),
                            b2f(mh2.y & 0xffffu), b2f(mh2.y >> 16) };
            union { __hip_bfloat16 h4[4]; uint2 u; } ox, oj;
            #pragma unroll
            for (int j = 0; j < 4; ++j) {
                const float mm = fminf(mD[j], fminf(mH[j], (j & 1) ? mW1 : mW0));
                ox.h4[j] = __float2bfloat16(xv[j]);
                oj.h4[j] = __float2bfloat16(fmaxf(0.0f, xv[j] - mm));
            }
            pk[it][0] = ox.u; pk[it][1] = oj.u;
        }
    }

    {
        #pragma unroll
        for (int it = 0; it < 8; ++it) {
            const int A = (it * 4 + wid) * 512 + sqq * 128 + row * 32 + colq * 8;
            *(uint2*)&ytile[A >> 1]             = pk[it][0];   // x part (cq 0..31)
            *(uint2*)&ytile[(A + 16384) >> 1]   = pk[it][1];   // xj part (cq 32..63)
        }
    }
    __syncthreads();                       // tile staged for all waves

    const uint_t lds_base = (uint_t)(uintptr_t)(__attribute__((address_space(3))) ushort_t*)&ytile[0];
    float* ob = out + (size_t)b * 128 * SVOL;

    const uint_t addrB = lds_base + (uint_t)(l4 * 1024 + l15 * 8);
    f32x4 acc[4][2] = {};
    #pragma unroll
    for (int ph4 = 0; ph4 < 4; ++ph4) {    // 4 phases x 16 tr_reads
        u32x2 lo[2][4], hi[2][4];
        #pragma unroll
        for (int kk = 0; kk < 2; ++kk)
            #pragma unroll
            for (int n = 0; n < 4; ++n) {
                const uint_t ad = addrB + (uint_t)((ph4 * 2 + kk) * 4096 + n * 128);
                asm volatile("ds_read_b64_tr_b16 %0, %2 offset:0\n\t"
                             "ds_read_b64_tr_b16 %1, %2 offset:512"
                             : "=&v"(lo[kk][n]), "=&v"(hi[kk][n]) : "v"(ad) : "memory");
            }
        asm volatile("s_waitcnt lgkmcnt(0)" ::: "memory");
        __builtin_amdgcn_sched_barrier(0);
        #pragma unroll
        for (int kk = 0; kk < 2; ++kk) {
            bf16x8 aw[2];
            #pragma unroll
            for (int m = 0; m < 2; ++m)
                aw[m] = *(const bf16x8*)(wp + ((size_t)m * 16 * 256 + (ph4 * 2 + kk) * 32));
            #pragma unroll
            for (int n = 0; n < 4; ++n) {
                union { u32x2 u2[2]; bf16x8 v; } cvt;
                cvt.u2[0] = lo[kk][n]; cvt.u2[1] = hi[kk][n];
                #pragma unroll
                for (int m = 0; m < 2; ++m)   // swapped operands: D rows = s
                    acc[n][m] = __builtin_amdgcn_mfma_f32_16x16x32_bf16(cvt.v, aw[m], acc[n][m], 0, 0, 0);
            }
        }
    }

    const int s_b = tile0 * 64;
    #pragma unroll
    for (int n = 0; n < 4; ++n)
        #pragma unroll
        for (int m = 0; m < 2; ++m) {
            const int o = wid * 32 + m * 16 + l15;
            const int s = s_b + n * 16 + l4 * 4;
            f32x4 r;
            #pragma unroll
            for (int j = 0; j < 4; ++j) r[j] = fmaxf(acc[n][m][j] + bv[m], 0.0f);
            *(f32x4*)(ob + (size_t)o * SVOL + s) = r;
        }
}

extern "C" void kernel_launch(void* const* d_in, const int* in_sizes, int n_in,
                              void* d_out, int out_size, void* d_ws, size_t ws_size,
                              hipStream_t stream) {
    const float* x    = (const float*)d_in[0];
    const float* W    = (const float*)d_in[1];
    const float* bias = (const float*)d_in[2];
    float* out = (float*)d_out;

    // d_ws (all bf16): Wb 64 KB | tabDp 6.75 MB | tabH 2.25 | tabW 2.25 | tabD 2.25
    ushort_t* Wb    = (ushort_t*)d_ws;
    ushort_t* tabDp = (ushort_t*)((char*)d_ws + 65536);
    ushort_t* tabH  = tabDp + (size_t)3 * 256 * 2 * HD;
    ushort_t* tabW  = tabH  + (size_t)256 * 2 * HD;
    ushort_t* tabD  = tabW  + (size_t)256 * 2 * HD;

    wconv_kernel<<<128, 256, 0, stream>>>(W, Wb);
    tables_kernel<<<dim3(256, 3), 256, 0, stream>>>(x, tabDp, tabH, tabW);
    merge_kernel<<<1152, 256, 0, stream>>>(tabDp, tabD);
    gemm_kernel<<<dim3(1728, 2), 256, 0, stream>>>(x, tabD, tabH, tabW, Wb, bias, out);
}